// Round 3
// baseline (824.142 us; speedup 1.0000x reference)
//
#include <hip/hip_runtime.h>

#define NN 50000
#define EE 400000

// workspace offsets (in floats)
#define WS_SUMS 0
#define WS_CNT  (NN*64)          // 3,200,000
#define WS_XW1  3250000          // N*128 floats

__device__ __forceinline__ void fma4(float4& a, float s, const float4& w){
  a.x = fmaf(s, w.x, a.x);
  a.y = fmaf(s, w.y, a.y);
  a.z = fmaf(s, w.z, a.z);
  a.w = fmaf(s, w.w, a.w);
}

__device__ __forceinline__ unsigned rotl32(unsigned v, int d){ return (v<<d)|(v>>(32-d)); }

// jax.random.normal(key(42), (50000,32), f32) under jax_threefry_partitionable=True
// (default since jax 0.4.36): per element i, counter pair = (hi32(i), lo32(i)) = (0, i),
// bits = x0_out ^ x1_out.  Then uniform via (bits>>9)|0x3f800000 - 1, scaled to
// [-0.99999994, 1), and sqrt(2)*ErfInv32 with w = -log1p(-u*u) (XLA formulation).
__device__ __forceinline__ float eps_at(unsigned idx){
  const unsigned k0 = 0u, k1 = 42u, k2 = 0x1BD11BDAu ^ 0u ^ 42u;
  unsigned x0 = 0u + k0, x1 = idx + k1;   // counter (0, idx)
  const int rotA[4] = {13,15,26,6};
  const int rotB[4] = {17,29,16,24};
  #pragma unroll
  for (int i=0;i<4;i++){ x0 += x1; x1 = rotl32(x1, rotA[i]); x1 ^= x0; }
  x0 += k1; x1 += k2 + 1u;
  #pragma unroll
  for (int i=0;i<4;i++){ x0 += x1; x1 = rotl32(x1, rotB[i]); x1 ^= x0; }
  x0 += k2; x1 += k0 + 2u;
  #pragma unroll
  for (int i=0;i<4;i++){ x0 += x1; x1 = rotl32(x1, rotA[i]); x1 ^= x0; }
  x0 += k0; x1 += k1 + 3u;
  #pragma unroll
  for (int i=0;i<4;i++){ x0 += x1; x1 = rotl32(x1, rotB[i]); x1 ^= x0; }
  x0 += k1; x1 += k2 + 4u;
  #pragma unroll
  for (int i=0;i<4;i++){ x0 += x1; x1 = rotl32(x1, rotA[i]); x1 ^= x0; }
  x0 += k2; x1 += k0 + 5u;
  unsigned bits = x0 ^ x1;   // partitionable 32-bit fold
  float f = __uint_as_float((bits >> 9) | 0x3f800000u) - 1.0f;  // [0,1)
  const float lo = -0.99999994f;                                 // nextafter(-1,0)
  float u = f * 2.0f + lo;                                       // (hi-lo) rounds to 2.0f
  u = fmaxf(u, lo);
  // XLA ErfInv32 (Giles coefficients, w = -log1p(-x*x))
  float w = -log1pf(-u*u);
  float p;
  if (w < 5.0f){
    w -= 2.5f;
    p = 2.81022636e-08f;
    p = fmaf(p,w, 3.43273939e-07f);
    p = fmaf(p,w,-3.5233877e-06f);
    p = fmaf(p,w,-4.39150654e-06f);
    p = fmaf(p,w, 0.00021858087f);
    p = fmaf(p,w,-0.00125372503f);
    p = fmaf(p,w,-0.00417768164f);
    p = fmaf(p,w, 0.246640727f);
    p = fmaf(p,w, 1.50140941f);
  } else {
    w = sqrtf(w) - 3.0f;
    p = -0.000200214257f;
    p = fmaf(p,w, 0.000100950558f);
    p = fmaf(p,w, 0.00134934322f);
    p = fmaf(p,w,-0.00367342844f);
    p = fmaf(p,w, 0.00573950773f);
    p = fmaf(p,w,-0.0076224613f);
    p = fmaf(p,w, 0.00943887047f);
    p = fmaf(p,w, 1.00167406f);
    p = fmaf(p,w, 2.83297682f);
  }
  return 1.41421356237f * (p * u);
}

// ---------------- kernel 1: xW1 = x @ W1[0:64,:]  [N,128] ----------------
__global__ __launch_bounds__(256) void k_xw1(const float* __restrict__ x,
                                             const float* __restrict__ W1,
                                             float* __restrict__ xW1){
  __shared__ __align__(16) float xt[64*64];
  const int tid = threadIdx.x;
  const int base = blockIdx.x * 64;
  #pragma unroll
  for (int i=0;i<4;i++){
    int f0 = (tid + 256*i)*4;
    int r = f0 >> 6, c = f0 & 63;
    int n = base + r;
    float4 v = make_float4(0.f,0.f,0.f,0.f);
    if (n < NN) v = *(const float4*)(x + n*64 + c);
    *(float4*)(xt + f0) = v;
  }
  __syncthreads();
  const int jq = tid & 31;     // 32 quads -> 128 cols
  const int rb = tid >> 5;     // 8 groups of 8 rows
  float4 acc[8];
  #pragma unroll
  for (int r=0;r<8;r++) acc[r] = make_float4(0.f,0.f,0.f,0.f);
  for (int k=0;k<64;k+=4){
    float4 w0 = *(const float4*)(W1 + (k+0)*128 + 4*jq);
    float4 w1 = *(const float4*)(W1 + (k+1)*128 + 4*jq);
    float4 w2 = *(const float4*)(W1 + (k+2)*128 + 4*jq);
    float4 w3 = *(const float4*)(W1 + (k+3)*128 + 4*jq);
    #pragma unroll
    for (int r=0;r<8;r++){
      float4 z = *(const float4*)(xt + (rb*8+r)*64 + k);
      fma4(acc[r], z.x, w0); fma4(acc[r], z.y, w1);
      fma4(acc[r], z.z, w2); fma4(acc[r], z.w, w3);
    }
  }
  #pragma unroll
  for (int r=0;r<8;r++){
    int n = base + rb*8 + r;
    if (n < NN) *(float4*)(xW1 + n*128 + 4*jq) = acc[r];
  }
}

// ---------------- kernel 2: edge MLP + scatter ----------------
#define H1STR 132   // padded stride (128+4) to break 4-way LDS bank conflicts
__global__ __launch_bounds__(256) void k_edge(const int* __restrict__ ei,
    const float* __restrict__ ea, const float* __restrict__ xW1,
    const float* __restrict__ W1, const float* __restrict__ b1,
    const float* __restrict__ g1, const float* __restrict__ be1,
    const float* __restrict__ W2, const float* __restrict__ b2,
    float* __restrict__ sums, float* __restrict__ cnt){
  __shared__ int rows_l[64];
  __shared__ int cols_l[64];
  __shared__ __align__(16) float sea[64*64];
  __shared__ __align__(16) float h1[64*H1STR];
  const int tid = threadIdx.x;
  const int base = blockIdx.x * 64;
  if (tid < 64){
    rows_l[tid] = ei[base + tid];
    cols_l[tid] = ei[EE + base + tid];
  }
  __syncthreads();
  #pragma unroll
  for (int i=0;i<4;i++){
    int f0 = (tid + 256*i)*4;
    int e = f0 >> 6, c = f0 & 63;
    *(float4*)(sea + f0) = *(const float4*)(ea + (base+e)*64 + c);
  }
  __syncthreads();
  // GEMM1: h1[e][128] = xW1[row[e]] + sea @ W1[64:,:] + b1
  {
    const int jq = tid & 31, rb = tid >> 5;
    float4 acc[8];
    #pragma unroll
    for (int r=0;r<8;r++)
      acc[r] = *(const float4*)(xW1 + (long long)rows_l[rb*8+r]*128 + 4*jq);
    for (int k=0;k<64;k+=4){
      float4 w0 = *(const float4*)(W1 + (64+k+0)*128 + 4*jq);
      float4 w1 = *(const float4*)(W1 + (64+k+1)*128 + 4*jq);
      float4 w2 = *(const float4*)(W1 + (64+k+2)*128 + 4*jq);
      float4 w3 = *(const float4*)(W1 + (64+k+3)*128 + 4*jq);
      #pragma unroll
      for (int r=0;r<8;r++){
        float4 z = *(const float4*)(sea + (rb*8+r)*64 + k);
        fma4(acc[r], z.x, w0); fma4(acc[r], z.y, w1);
        fma4(acc[r], z.z, w2); fma4(acc[r], z.w, w3);
      }
    }
    float4 bb = *(const float4*)(b1 + 4*jq);
    #pragma unroll
    for (int r=0;r<8;r++){
      float4 v = acc[r];
      v.x += bb.x; v.y += bb.y; v.z += bb.z; v.w += bb.w;
      *(float4*)(h1 + (rb*8+r)*H1STR + 4*jq) = v;
    }
  }
  __syncthreads();
  // LayerNorm(128) + ReLU, wave per row
  {
    const int wv = tid >> 6, lane = tid & 63;
    const float gA = g1[lane], gB = g1[lane+64];
    const float bA = be1[lane], bB = be1[lane+64];
    for (int r = wv*16; r < wv*16 + 16; ++r){
      float a = h1[r*H1STR + lane];
      float b = h1[r*H1STR + 64 + lane];
      float s = a + b, ss = fmaf(a,a,b*b);
      #pragma unroll
      for (int off=32; off; off>>=1){
        s  += __shfl_xor(s, off);
        ss += __shfl_xor(ss, off);
      }
      float mean = s * (1.0f/128.0f);
      float var  = ss * (1.0f/128.0f) - mean*mean;
      float inv = rsqrtf(var + 1e-5f);
      h1[r*H1STR + lane]      = fmaxf(fmaf((a-mean)*inv, gA, bA), 0.f);
      h1[r*H1STR + 64 + lane] = fmaxf(fmaf((b-mean)*inv, gB, bB), 0.f);
    }
  }
  __syncthreads();
  // GEMM2: h @ W2 + b2, atomic scatter into sums[col]
  {
    const int jq = tid & 15, rb = tid >> 4;
    float4 acc[4];
    #pragma unroll
    for (int r=0;r<4;r++) acc[r] = make_float4(0.f,0.f,0.f,0.f);
    for (int k=0;k<128;k+=4){
      float4 w0 = *(const float4*)(W2 + (k+0)*64 + 4*jq);
      float4 w1 = *(const float4*)(W2 + (k+1)*64 + 4*jq);
      float4 w2 = *(const float4*)(W2 + (k+2)*64 + 4*jq);
      float4 w3 = *(const float4*)(W2 + (k+3)*64 + 4*jq);
      #pragma unroll
      for (int r=0;r<4;r++){
        float4 z = *(const float4*)(h1 + (rb*4+r)*H1STR + k);
        fma4(acc[r], z.x, w0); fma4(acc[r], z.y, w1);
        fma4(acc[r], z.z, w2); fma4(acc[r], z.w, w3);
      }
    }
    float4 bb = *(const float4*)(b2 + 4*jq);
    #pragma unroll
    for (int r=0;r<4;r++){
      int c = cols_l[rb*4+r];
      float* dst = sums + (long long)c*64 + 4*jq;
      atomicAdd(dst+0, acc[r].x + bb.x);
      atomicAdd(dst+1, acc[r].y + bb.y);
      atomicAdd(dst+2, acc[r].z + bb.z);
      atomicAdd(dst+3, acc[r].w + bb.w);
    }
  }
  if (tid < 64) atomicAdd(cnt + cols_l[tid], 1.0f);
}

// ---------------- kernel 3: node MLP + heads + reparam ----------------
#define T2STR 132
#define ZSSTR 36
__global__ __launch_bounds__(256) void k_node(const float* __restrict__ x,
    const float* __restrict__ u, const int* __restrict__ batch,
    const float* __restrict__ sums, const float* __restrict__ cnt,
    const float* __restrict__ W3, const float* __restrict__ b3,
    const float* __restrict__ g3, const float* __restrict__ be3,
    const float* __restrict__ W4, const float* __restrict__ b4,
    const float* __restrict__ g4, const float* __restrict__ be4,
    const float* __restrict__ Wm, const float* __restrict__ bm,
    const float* __restrict__ Wv, const float* __restrict__ bv,
    const float* __restrict__ Wx, const float* __restrict__ bx,
    float* __restrict__ out){
  __shared__ __align__(16) float zt[32*160];   // reused: t2 (stride 132), zs (stride 36)
  __shared__ __align__(16) float h3[32*256];   // reused: hm (32x64 mu|lv)
  __shared__ float rcnt_l[32];
  __shared__ int batch_l[32];
  const int tid = threadIdx.x;
  const int base = blockIdx.x * 32;
  if (tid < 32){
    int n = base + tid;
    float c = (n < NN) ? cnt[n] : 1.0f;
    rcnt_l[tid] = 1.0f / fmaxf(c, 1.0f);
    batch_l[tid] = (n < NN) ? batch[n] : 0;
  }
  __syncthreads();
  // build z = [x | sums/deg | u[batch]]  (32 x 160)
  #pragma unroll
  for (int i=0;i<5;i++){
    int f0 = (tid + 256*i)*4;
    int r = f0 / 160;
    int c = f0 - r*160;
    int n = base + r;
    float4 v = make_float4(0.f,0.f,0.f,0.f);
    if (n < NN){
      if (c < 64) v = *(const float4*)(x + n*64 + c);
      else if (c < 128){
        v = *(const float4*)(sums + n*64 + (c-64));
        float rc = rcnt_l[r];
        v.x *= rc; v.y *= rc; v.z *= rc; v.w *= rc;
      } else {
        v = *(const float4*)(u + batch_l[r]*32 + (c-128));
      }
    }
    *(float4*)(zt + f0) = v;
  }
  __syncthreads();
  // GEMM1: h3[32][256] = z @ W3 + b3
  {
    const int jq = tid & 63, rb = tid >> 6;   // 4 groups x 8 rows
    float4 acc[8];
    #pragma unroll
    for (int r=0;r<8;r++) acc[r] = make_float4(0.f,0.f,0.f,0.f);
    for (int k=0;k<160;k+=4){
      float4 w0 = *(const float4*)(W3 + (k+0)*256 + 4*jq);
      float4 w1 = *(const float4*)(W3 + (k+1)*256 + 4*jq);
      float4 w2 = *(const float4*)(W3 + (k+2)*256 + 4*jq);
      float4 w3v= *(const float4*)(W3 + (k+3)*256 + 4*jq);
      #pragma unroll
      for (int r=0;r<8;r++){
        float4 z = *(const float4*)(zt + (rb*8+r)*160 + k);
        fma4(acc[r], z.x, w0); fma4(acc[r], z.y, w1);
        fma4(acc[r], z.z, w2); fma4(acc[r], z.w, w3v);
      }
    }
    float4 bb = *(const float4*)(b3 + 4*jq);
    #pragma unroll
    for (int r=0;r<8;r++){
      float4 v = acc[r];
      v.x += bb.x; v.y += bb.y; v.z += bb.z; v.w += bb.w;
      *(float4*)(h3 + (rb*8+r)*256 + 4*jq) = v;
    }
  }
  __syncthreads();
  // LN(256) + ReLU, wave per row
  {
    const int wv = tid >> 6, lane = tid & 63;
    float gg[4], bb[4];
    #pragma unroll
    for (int m=0;m<4;m++){ gg[m] = g3[lane+64*m]; bb[m] = be3[lane+64*m]; }
    for (int r = wv*8; r < wv*8+8; ++r){
      float v[4];
      #pragma unroll
      for (int m=0;m<4;m++) v[m] = h3[r*256 + lane + 64*m];
      float s = 0.f, ss = 0.f;
      #pragma unroll
      for (int m=0;m<4;m++){ s += v[m]; ss = fmaf(v[m], v[m], ss); }
      #pragma unroll
      for (int off=32; off; off>>=1){ s += __shfl_xor(s, off); ss += __shfl_xor(ss, off); }
      float mean = s * (1.0f/256.0f);
      float var  = ss * (1.0f/256.0f) - mean*mean;
      float inv = rsqrtf(var + 1e-5f);
      #pragma unroll
      for (int m=0;m<4;m++)
        h3[r*256 + lane + 64*m] = fmaxf(fmaf((v[m]-mean)*inv, gg[m], bb[m]), 0.f);
    }
  }
  __syncthreads();
  // GEMM2: t2[32][128] = h3 @ W4 + b4  (t2 overlays zt, stride 132)
  {
    const int jq = tid & 31, rb = tid >> 5;   // 8 groups x 4 rows
    float4 acc[4];
    #pragma unroll
    for (int r=0;r<4;r++) acc[r] = make_float4(0.f,0.f,0.f,0.f);
    for (int k=0;k<256;k+=4){
      float4 w0 = *(const float4*)(W4 + (k+0)*128 + 4*jq);
      float4 w1 = *(const float4*)(W4 + (k+1)*128 + 4*jq);
      float4 w2 = *(const float4*)(W4 + (k+2)*128 + 4*jq);
      float4 w3 = *(const float4*)(W4 + (k+3)*128 + 4*jq);
      #pragma unroll
      for (int r=0;r<4;r++){
        float4 z = *(const float4*)(h3 + (rb*4+r)*256 + k);
        fma4(acc[r], z.x, w0); fma4(acc[r], z.y, w1);
        fma4(acc[r], z.z, w2); fma4(acc[r], z.w, w3);
      }
    }
    float4 bb = *(const float4*)(b4 + 4*jq);
    #pragma unroll
    for (int r=0;r<4;r++){
      float4 v = acc[r];
      v.x += bb.x; v.y += bb.y; v.z += bb.z; v.w += bb.w;
      *(float4*)(zt + (rb*4+r)*T2STR + 4*jq) = v;
    }
  }
  __syncthreads();
  // LN(128) + ReLU on t2
  {
    const int wv = tid >> 6, lane = tid & 63;
    const float gA = g4[lane], gB = g4[lane+64];
    const float bA = be4[lane], bB = be4[lane+64];
    for (int r = wv*8; r < wv*8+8; ++r){
      float a = zt[r*T2STR + lane], b = zt[r*T2STR + 64 + lane];
      float s = a + b, ss = fmaf(a,a,b*b);
      #pragma unroll
      for (int off=32; off; off>>=1){ s += __shfl_xor(s, off); ss += __shfl_xor(ss, off); }
      float mean = s * (1.0f/128.0f);
      float var  = ss * (1.0f/128.0f) - mean*mean;
      float inv = rsqrtf(var + 1e-5f);
      zt[r*T2STR + lane]      = fmaxf(fmaf((a-mean)*inv, gA, bA), 0.f);
      zt[r*T2STR + 64 + lane] = fmaxf(fmaf((b-mean)*inv, gB, bB), 0.f);
    }
  }
  __syncthreads();
  // heads: hm[32][64] = t2 @ [Wm|Wv] + [bm|bv]; also store mu/lv to out
  {
    const int jq = tid & 15, rb = tid >> 4;   // 16 groups x 2 rows
    const float* Wp = (jq < 8) ? Wm : Wv;
    const int cq = (jq & 7) * 4;
    float4 acc[2];
    #pragma unroll
    for (int r=0;r<2;r++) acc[r] = make_float4(0.f,0.f,0.f,0.f);
    for (int k=0;k<128;k+=4){
      float4 w0 = *(const float4*)(Wp + (k+0)*32 + cq);
      float4 w1 = *(const float4*)(Wp + (k+1)*32 + cq);
      float4 w2 = *(const float4*)(Wp + (k+2)*32 + cq);
      float4 w3 = *(const float4*)(Wp + (k+3)*32 + cq);
      #pragma unroll
      for (int r=0;r<2;r++){
        float4 z = *(const float4*)(zt + (rb*2+r)*T2STR + k);
        fma4(acc[r], z.x, w0); fma4(acc[r], z.y, w1);
        fma4(acc[r], z.z, w2); fma4(acc[r], z.w, w3);
      }
    }
    const float* bp = (jq < 8) ? bm : bv;
    float4 bb = *(const float4*)(bp + cq);
    const long long sec = (jq < 8) ? (long long)NN*64 : ((long long)NN*64 + (long long)NN*32);
    #pragma unroll
    for (int r=0;r<2;r++){
      float4 v = acc[r];
      v.x += bb.x; v.y += bb.y; v.z += bb.z; v.w += bb.w;
      int rr = rb*2 + r;
      *(float4*)(h3 + rr*64 + ((jq<8)?0:32) + cq) = v;
      int n = base + rr;
      if (n < NN) *(float4*)(out + sec + (long long)n*32 + cq) = v;
    }
  }
  __syncthreads();
  // reparameterize: zs = mu + eps * exp(0.5*lv)   (zs overlays zt, stride 36)
  {
    #pragma unroll
    for (int i=0;i<4;i++){
      int l = tid + 256*i;
      int r = l >> 5, jj = l & 31;
      float mu = h3[r*64 + jj];
      float lv = h3[r*64 + 32 + jj];
      unsigned idx = (unsigned)((base + r)*32 + jj);
      float e = eps_at(idx);
      zt[r*ZSSTR + jj] = fmaf(e, expf(0.5f*lv), mu);
    }
  }
  __syncthreads();
  // out[32][64] = zs @ Wx + bx
  {
    const int jq = tid & 15, rb = tid >> 4;
    float4 acc[2];
    #pragma unroll
    for (int r=0;r<2;r++) acc[r] = make_float4(0.f,0.f,0.f,0.f);
    for (int k=0;k<32;k+=4){
      float4 w0 = *(const float4*)(Wx + (k+0)*64 + 4*jq);
      float4 w1 = *(const float4*)(Wx + (k+1)*64 + 4*jq);
      float4 w2 = *(const float4*)(Wx + (k+2)*64 + 4*jq);
      float4 w3 = *(const float4*)(Wx + (k+3)*64 + 4*jq);
      #pragma unroll
      for (int r=0;r<2;r++){
        float4 z = *(const float4*)(zt + (rb*2+r)*ZSSTR + k);
        fma4(acc[r], z.x, w0); fma4(acc[r], z.y, w1);
        fma4(acc[r], z.z, w2); fma4(acc[r], z.w, w3);
      }
    }
    float4 bb = *(const float4*)(bx + 4*jq);
    #pragma unroll
    for (int r=0;r<2;r++){
      int n = base + rb*2 + r;
      if (n < NN){
        float4 v = acc[r];
        v.x += bb.x; v.y += bb.y; v.z += bb.z; v.w += bb.w;
        *(float4*)(out + (long long)n*64 + 4*jq) = v;
      }
    }
  }
}

extern "C" void kernel_launch(void* const* d_in, const int* in_sizes, int n_in,
                              void* d_out, int out_size, void* d_ws, size_t ws_size,
                              hipStream_t stream) {
  const float* x     = (const float*)d_in[0];
  const int*   ei    = (const int*)d_in[1];     // int32 (JAX x64 disabled)
  const float* ea    = (const float*)d_in[2];
  const float* u     = (const float*)d_in[3];
  const int*   batch = (const int*)d_in[4];     // int32
  // d_in[5] = goal (unused by reference)
  const float* W1 = (const float*)d_in[6];
  const float* b1 = (const float*)d_in[7];
  const float* g1 = (const float*)d_in[8];
  const float* be1= (const float*)d_in[9];
  const float* W2 = (const float*)d_in[10];
  const float* b2 = (const float*)d_in[11];
  const float* W3 = (const float*)d_in[12];
  const float* b3 = (const float*)d_in[13];
  const float* g3 = (const float*)d_in[14];
  const float* be3= (const float*)d_in[15];
  const float* W4 = (const float*)d_in[16];
  const float* b4 = (const float*)d_in[17];
  const float* g4 = (const float*)d_in[18];
  const float* be4= (const float*)d_in[19];
  const float* Wm = (const float*)d_in[20];
  const float* bm = (const float*)d_in[21];
  const float* Wv = (const float*)d_in[22];
  const float* bv = (const float*)d_in[23];
  const float* Wx = (const float*)d_in[24];
  const float* bx = (const float*)d_in[25];

  float* ws   = (float*)d_ws;
  float* sums = ws + WS_SUMS;
  float* cnt  = ws + WS_CNT;
  float* xW1  = ws + WS_XW1;
  float* out  = (float*)d_out;

  // zero scatter accumulators (sums + cnt are contiguous)
  hipMemsetAsync(sums, 0, (size_t)(NN*64 + NN)*sizeof(float), stream);

  k_xw1 <<<(NN+63)/64, 256, 0, stream>>>(x, W1, xW1);
  k_edge<<<EE/64,      256, 0, stream>>>(ei, ea, xW1, W1, b1, g1, be1, W2, b2, sums, cnt);
  k_node<<<(NN+31)/32, 256, 0, stream>>>(x, u, batch, sums, cnt,
                                         W3,b3,g3,be3, W4,b4,g4,be4,
                                         Wm,bm, Wv,bv, Wx,bx, out);
}